// Round 2
// 412.682 us; speedup vs baseline: 1.1435x; 1.1435x over previous
//
#include <hip/hip_runtime.h>
#include <hip/hip_bf16.h>
#include <math.h>

// Problem constants
#define BB 64
#define TT 128
#define VV 25
#define CC 128
#define KK 128
#define RR 32
#define TG 4    // timesteps per kF block (= waves per block)

typedef __attribute__((ext_vector_type(8))) short bf16x8;
typedef __attribute__((ext_vector_type(4))) float f32x4;

// bf16 helpers (RNE)
static __device__ __forceinline__ short f2bf(float f) {
    union { float f; unsigned u; } a; a.f = f;
    unsigned r = a.u + 0x7fffu + ((a.u >> 16) & 1u);
    return (short)(r >> 16);
}
static __device__ __forceinline__ float bf2f(short s) {
    union { unsigned u; float f; } a; a.u = ((unsigned)(unsigned short)s) << 16;
    return a.f;
}

// Workspace layout (float offsets)
#define WS_XBAR 0              // [B,V,C]      204800
#define WS_PHIX 204800         // [B,V,K]      204800
#define WS_THX  409600         // [B,V,K]      204800
#define WS_HBAR 614400         // [B,V,K]      204800
#define WS_XQ   819200         // [B,V,K]      204800
#define WS_XK   1024000        // [B,V,K]      204800
#define WS_CA   1228800        // [B,K]        8192
#define WS_GATE 1236992        // [B,K]        8192
#define WS_AT   1245184        // Atv [B][V=u][K][32 v-padded] bf16: 6.55M shorts (3.28M floats)
#define WS_BT   6365184        // [K][C]       16384 bf16 (xi_w transposed)

// ---------------------------------------------------------------------------
// Kernel A: xbar[b,v,c] = mean_t x[b,t,v,c].  One 256-thr block per (b,v) row.
__global__ __launch_bounds__(256) void kA(const float* __restrict__ x, float* __restrict__ xbar) {
    int row = blockIdx.x;                 // b*V + v
    int b = row / VV, v = row % VV;
    int tq = threadIdx.x >> 5, cq = threadIdx.x & 31;
    const float4* x4 = (const float4*)x;
    size_t base = ((size_t)b * TT * VV + v) * 32 + cq;
    float sx = 0.f, sy = 0.f, sz = 0.f, sw = 0.f;
    #pragma unroll 4
    for (int i = 0; i < 16; ++i) {
        float4 a = x4[base + (size_t)(tq * 16 + i) * VV * 32];
        sx += a.x; sy += a.y; sz += a.z; sw += a.w;
    }
    __shared__ float4 red[8][32];
    red[tq][cq] = (float4){sx, sy, sz, sw};
    __syncthreads();
    if (tq == 0) {
        float4 o = red[0][cq];
        #pragma unroll
        for (int j = 1; j < 8; ++j) {
            float4 a = red[j][cq];
            o.x += a.x; o.y += a.y; o.z += a.z; o.w += a.w;
        }
        o.x *= (1.f/TT); o.y *= (1.f/TT); o.z *= (1.f/TT); o.w *= (1.f/TT);
        ((float4*)xbar)[(size_t)row * 32 + cq] = o;
    }
}

// ---------------------------------------------------------------------------
// Kernel BT: BT[n][c] = bf16(xi_w[c][n])
__global__ __launch_bounds__(256) void kBT(const float* __restrict__ xw, short* __restrict__ BT) {
    for (int i = threadIdx.x + blockIdx.x * 256; i < KK * CC; i += 256 * 64) {
        int n = i >> 7, c = i & 127;
        BT[i] = f2bf(xw[c * KK + n]);
    }
}

// ---------------------------------------------------------------------------
// Kernel B1: per (b,v): phi_x / theta_x / Hbar rows from xbar.
__global__ __launch_bounds__(128) void kB1(const float* __restrict__ xbar,
        const float* __restrict__ pw, const float* __restrict__ pb,
        const float* __restrict__ tw, const float* __restrict__ tb,
        const float* __restrict__ xw, const float* __restrict__ xbias,
        float* __restrict__ phix, float* __restrict__ thx, float* __restrict__ hbar) {
    int bv = blockIdx.x;
    int k = threadIdx.x;
    __shared__ float xv[CC];
    xv[k] = xbar[(size_t)bv * CC + k];
    __syncthreads();
    float sp = pb[k], st = tb[k], sh = xbias[k];
    #pragma unroll 4
    for (int c = 0; c < CC; ++c) {
        float xc = xv[c];
        sp = fmaf(xc, pw[c*KK + k], sp);
        st = fmaf(xc, tw[c*KK + k], st);
        sh = fmaf(xc, xw[c*KK + k], sh);
    }
    phix[(size_t)bv*KK + k] = sp;
    thx [(size_t)bv*KK + k] = st;
    hbar[(size_t)bv*KK + k] = sh;
}

// ---------------------------------------------------------------------------
// Kernel B2: per (b,i) block: Atv[b,i,k,v32] (bf16, v-padded to 32) for all j=v.
// All s[]/vals[]/dw[] accesses are fully unrolled (static indices) so they stay
// in VGPRs — the previous version's partially-unrolled final loop demoted s[]
// to scratch.
__global__ __launch_bounds__(128) void kB2(const float* __restrict__ phix, const float* __restrict__ thx,
        const float* __restrict__ kw, const float* __restrict__ kb,
        const float* __restrict__ A, const float* __restrict__ lam,
        short* __restrict__ Atv) {
    int bi = blockIdx.x;                 // b*V + i
    int b = bi / VV, i = bi % VV;
    int k = threadIdx.x;
    __shared__ float f[VV][132];
    float ph = phix[((size_t)b*VV + i)*KK + k];
    #pragma unroll 5
    for (int j = 0; j < VV; ++j)
        f[j][k] = tanhf(ph - thx[((size_t)b*VV + j)*KK + k]);
    __syncthreads();
    float s[VV];
    float bias = kb[k];
    #pragma unroll
    for (int j = 0; j < VV; ++j) s[j] = bias;
    #pragma unroll 2
    for (int c = 0; c < CC; c += 4) {
        float w0 = kw[(c+0)*KK + k];
        float w1 = kw[(c+1)*KK + k];
        float w2 = kw[(c+2)*KK + k];
        float w3 = kw[(c+3)*KK + k];
        #pragma unroll
        for (int j = 0; j < VV; ++j) {
            float4 fv = *(const float4*)&f[j][c];
            float t = fmaf(fv.x, w0, fmaf(fv.y, w1, fmaf(fv.z, w2, fv.w * w3)));
            s[j] += t;
        }
    }
    float l = lam[0];
    float vals[32];
    #pragma unroll
    for (int j = 0; j < VV; ++j)
        vals[j] = A[((size_t)k*VV + i)*VV + j] + l * s[j];
    #pragma unroll
    for (int j = VV; j < 32; ++j) vals[j] = 0.f;
    unsigned dw[16];
    #pragma unroll
    for (int m = 0; m < 16; ++m)
        dw[m] = (unsigned)(unsigned short)f2bf(vals[2*m])
              | ((unsigned)(unsigned short)f2bf(vals[2*m+1]) << 16);
    uint4* dst = (uint4*)(Atv + ((size_t)bi * KK + k) * 32);
    dst[0] = make_uint4(dw[0],  dw[1],  dw[2],  dw[3]);
    dst[1] = make_uint4(dw[4],  dw[5],  dw[6],  dw[7]);
    dst[2] = make_uint4(dw[8],  dw[9],  dw[10], dw[11]);
    dst[3] = make_uint4(dw[12], dw[13], dw[14], dw[15]);
}

// ---------------------------------------------------------------------------
// Kernel B34: per (b,u): Zbar row (in LDS) then XQ/XK rows.  At read is 4x
// dwordx4 from the packed Atv layout (v ascending lo/hi -> identical fp32
// accumulation order as before).
__global__ __launch_bounds__(128) void kB34(const short* __restrict__ Atv, const float* __restrict__ hbar,
        const float* __restrict__ qw, const float* __restrict__ qb,
        const float* __restrict__ kw, const float* __restrict__ kb,
        float* __restrict__ XQ, float* __restrict__ XK) {
    int bu = blockIdx.x;
    int b = bu / VV;
    int k = threadIdx.x;
    __shared__ float zb[132];
    const float* hb = hbar + (size_t)b * VV * KK + k;
    const uint4* av = (const uint4*)(Atv + ((size_t)bu * KK + k) * 32);
    uint4 a0 = av[0], a1 = av[1], a2 = av[2], a3 = av[3];
    float s = 0.f;
#define KB34S(dd, v0) { \
    float lo_ = __uint_as_float((unsigned)(dd) << 16); \
    float hi_ = __uint_as_float((unsigned)(dd) & 0xffff0000u); \
    s = fmaf(lo_, hb[(v0)*KK], s); s = fmaf(hi_, hb[((v0)+1)*KK], s); }
    KB34S(a0.x, 0)  KB34S(a0.y, 2)  KB34S(a0.z, 4)  KB34S(a0.w, 6)
    KB34S(a1.x, 8)  KB34S(a1.y, 10) KB34S(a1.z, 12) KB34S(a1.w, 14)
    KB34S(a2.x, 16) KB34S(a2.y, 18) KB34S(a2.z, 20) KB34S(a2.w, 22)
    { float lo_ = __uint_as_float((unsigned)a3.x << 16); s = fmaf(lo_, hb[24*KK], s); }
#undef KB34S
    zb[k] = s;
    __syncthreads();
    float q = qb[k], kk2 = kb[k];
    #pragma unroll 2
    for (int c = 0; c < CC; c += 4) {
        float4 zv = *(const float4*)&zb[c];
        float q0 = qw[(c+0)*KK + k], q1 = qw[(c+1)*KK + k];
        float q2 = qw[(c+2)*KK + k], q3 = qw[(c+3)*KK + k];
        float k0 = kw[(c+0)*KK + k], k1 = kw[(c+1)*KK + k];
        float k2 = kw[(c+2)*KK + k], k3 = kw[(c+3)*KK + k];
        q   = fmaf(zv.x, q0, fmaf(zv.y, q1, fmaf(zv.z, q2, fmaf(zv.w, q3, q))));
        kk2 = fmaf(zv.x, k0, fmaf(zv.y, k1, fmaf(zv.z, k2, fmaf(zv.w, k3, kk2))));
    }
    XQ[(size_t)bu*KK + k] = q;
    XK[(size_t)bu*KK + k] = kk2;
}

// ---------------------------------------------------------------------------
// Kernel B5: ca[b,k] = sum_v Hbar * mean_u softmax_v(q_u k_v / sqrt(T))
__global__ __launch_bounds__(64) void kB5(const float* __restrict__ XQ, const float* __restrict__ XK,
        const float* __restrict__ hbar, float* __restrict__ ca) {
    int b = blockIdx.x >> 7;
    int k = blockIdx.x & 127;
    int tid = threadIdx.x;
    __shared__ float qv[VV], kv[VV], hv[VV], m[VV], dinv[VV];
    if (tid < VV) {
        qv[tid] = XQ[((size_t)b*VV + tid)*KK + k];
        kv[tid] = XK[((size_t)b*VV + tid)*KK + k];
        hv[tid] = hbar[((size_t)b*VV + tid)*KK + k];
    }
    __syncthreads();
    const float invs = 0.08838834764831845f;   // 1/sqrt(128)
    if (tid < VV) {
        float q = qv[tid];
        float mx = -1e30f;
        #pragma unroll
        for (int v = 0; v < VV; ++v) mx = fmaxf(mx, q * kv[v] * invs);
        float d = 0.f;
        #pragma unroll
        for (int v = 0; v < VV; ++v) d += expf(q * kv[v] * invs - mx);
        m[tid] = mx; dinv[tid] = 1.f / d;
    }
    __syncthreads();
    float contrib = 0.f;
    if (tid < VV) {
        float kkv = kv[tid];
        float s = 0.f;
        #pragma unroll
        for (int u = 0; u < VV; ++u) s += expf(qv[u] * kkv * invs - m[u]) * dinv[u];
        contrib = s * (1.f / VV) * hv[tid];
    }
    #pragma unroll
    for (int off = 32; off > 0; off >>= 1) contrib += __shfl_down(contrib, off);
    if (tid == 0) ca[(size_t)b*KK + k] = contrib;
}

// ---------------------------------------------------------------------------
// Kernel B6: gate = sigmoid(gelu(LN(ca@ca1_w+ca1_b)) @ ca2_w + ca2_b)
__global__ __launch_bounds__(128) void kB6(const float* __restrict__ ca,
        const float* __restrict__ w1, const float* __restrict__ b1,
        const float* __restrict__ lw, const float* __restrict__ lb,
        const float* __restrict__ w2, const float* __restrict__ b2,
        float* __restrict__ gate) {
    int b = blockIdx.x;
    int tid = threadIdx.x;
    __shared__ float cas[KK], t1[RR], c1[RR];
    cas[tid] = ca[(size_t)b*KK + tid];
    __syncthreads();
    if (tid < RR) {
        float s = b1[tid];
        for (int c = 0; c < KK; ++c) s = fmaf(cas[c], w1[c*RR + tid], s);
        t1[tid] = s;
    }
    __syncthreads();
    if (tid < RR) {
        float mu = 0.f;
        #pragma unroll
        for (int j = 0; j < RR; ++j) mu += t1[j];
        mu *= (1.f / RR);
        float var = 0.f;
        #pragma unroll
        for (int j = 0; j < RR; ++j) { float d = t1[j] - mu; var = fmaf(d, d, var); }
        var *= (1.f / RR);
        float xn = (t1[tid] - mu) * rsqrtf(var + 1e-5f) * lw[tid] + lb[tid];
        c1[tid] = 0.5f * xn * (1.f + erff(xn * 0.70710678118654752f));
    }
    __syncthreads();
    float g = b2[tid];
    #pragma unroll
    for (int r = 0; r < RR; ++r) g = fmaf(c1[r], w2[r*KK + tid], g);
    gate[(size_t)b*KK + tid] = 1.f / (1.f + expf(-g));
}

// ---------------------------------------------------------------------------
// Kernel F (fused H+Z): block = (b, 4 timesteps), 256 threads / 4 waves.
// Phase 1: wave w computes H[t0+w, v, k] via MFMA, writes bf16 H tile to LDS.
// Phase 2: thread (k=tid&127, g=tid>>7) handles tt in {2g,2g+1}:
//          h[tt][v] -> regs; barrier (all h reads done); then per u the gated
//          graph-conv z is written DIRECTLY to LDS (no private z arrays ->
//          no scratch).  At comes from packed Atv[b][u][k][v32]: 4 dwordx4
//          per u with register prefetch of u+1, instead of 625 scalar ushort
//          loads per thread.
#define HP 132  // LDS row pitch (shorts)
__global__ __launch_bounds__(256, 3) void kF(const float* __restrict__ x,
        const short* __restrict__ BT, const float* __restrict__ xbias,
        const short* __restrict__ Atv, const float* __restrict__ gate,
        const float* __restrict__ lw, const float* __restrict__ lb,
        float* __restrict__ out) {
    int b  = blockIdx.x >> 5;         // b-major: 32 consecutive blocks share b (L2 Atv reuse)
    int tg = blockIdx.x & 31;
    int t0 = tg * TG;
    int tid = threadIdx.x;
    int wave = tid >> 6, lane = tid & 63;
    int l15 = lane & 15, quad = lane >> 4;

    __shared__ short Hs[TG * 32 * HP];      // 33792 B
    __shared__ float ms[TG * 32], rs[TG * 32];

    // ---- Phase 1: MFMA H for timestep t0+wave ----
    {
        const float* xw_base = x + ((size_t)(b * TT + t0 + wave) * VV) * CC;
        f32x4 acc[2][8];
        #pragma unroll
        for (int rt = 0; rt < 2; ++rt)
            #pragma unroll
            for (int ct = 0; ct < 8; ++ct)
                acc[rt][ct] = (f32x4){0.f, 0.f, 0.f, 0.f};

        int va0 = l15;            // rt=0 A-row
        int va1 = 16 + l15;       // rt=1 A-row
        if (va1 > VV - 1) va1 = VV - 1;   // clamp pad rows (results unused)

        #pragma unroll
        for (int s = 0; s < 4; ++s) {
            bf16x8 afr[2];
            #pragma unroll
            for (int rt = 0; rt < 2; ++rt) {
                const float* ap = xw_base + (size_t)(rt ? va1 : va0) * CC + s*32 + quad*8;
                float4 a0 = *(const float4*)ap;
                float4 a1 = *(const float4*)(ap + 4);
                union { bf16x8 v; short h[8]; } u;
                u.h[0] = f2bf(a0.x); u.h[1] = f2bf(a0.y); u.h[2] = f2bf(a0.z); u.h[3] = f2bf(a0.w);
                u.h[4] = f2bf(a1.x); u.h[5] = f2bf(a1.y); u.h[6] = f2bf(a1.z); u.h[7] = f2bf(a1.w);
                afr[rt] = u.v;
            }
            #pragma unroll
            for (int ct = 0; ct < 8; ++ct) {
                bf16x8 bfr = *(const bf16x8*)(BT + (ct*16 + l15) * CC + s*32 + quad*8);
                acc[0][ct] = __builtin_amdgcn_mfma_f32_16x16x32_bf16(afr[0], bfr, acc[0][ct], 0, 0, 0);
                acc[1][ct] = __builtin_amdgcn_mfma_f32_16x16x32_bf16(afr[1], bfr, acc[1][ct], 0, 0, 0);
            }
        }
        // write H tile to LDS: row v = rt*16 + quad*4 + i, col k = ct*16 + l15
        #pragma unroll
        for (int ct = 0; ct < 8; ++ct) {
            float bias = xbias[ct*16 + l15];
            #pragma unroll
            for (int rt = 0; rt < 2; ++rt) {
                int vbase = rt*16 + quad*4;
                #pragma unroll
                for (int i = 0; i < 4; ++i)
                    Hs[(wave*32 + vbase + i) * HP + ct*16 + l15] = f2bf(acc[rt][ct][i] + bias);
            }
        }
    }

    // ---- Phase 2 setup: issue global loads early (independent of LDS) ----
    int k = tid & 127, g = tid >> 7;
    int tt0 = 2*g, tt1 = 2*g + 1;
    float gv = gate[(size_t)b * KK + k];
    const uint4* ap = (const uint4*)(Atv + ((size_t)(b * VV) * KK + k) * 32);
    uint4 c0 = ap[0], c1 = ap[1], c2 = ap[2], c3 = ap[3];   // u=0 tile in flight

    __syncthreads();   // H tile complete

    float h0[VV], h1[VV];
    #pragma unroll
    for (int v = 0; v < VV; ++v) {
        h0[v] = bf2f(Hs[(tt0*32 + v) * HP + k]);
        h1[v] = bf2f(Hs[(tt1*32 + v) * HP + k]);
    }
    __syncthreads();   // all Hs reads done; rows free for z overwrite

#define CONVSTEP(dd, v0) { \
    float lo_ = __uint_as_float((unsigned)(dd) << 16); \
    float hi_ = __uint_as_float((unsigned)(dd) & 0xffff0000u); \
    za0 = fmaf(lo_, h0[v0], za0); zb0 = fmaf(hi_, h0[(v0)+1], zb0); \
    za1 = fmaf(lo_, h1[v0], za1); zb1 = fmaf(hi_, h1[(v0)+1], zb1); }

    #pragma unroll 1
    for (int u = 0; u < VV; ++u) {
        const uint4* np = ap + ((u < VV-1) ? (KK*4) : 0);   // prefetch u+1 (clamped)
        uint4 n0 = np[0], n1 = np[1], n2 = np[2], n3 = np[3];
        float za0 = 0.f, zb0 = 0.f, za1 = 0.f, zb1 = 0.f;
        CONVSTEP(c0.x, 0)  CONVSTEP(c0.y, 2)  CONVSTEP(c0.z, 4)  CONVSTEP(c0.w, 6)
        CONVSTEP(c1.x, 8)  CONVSTEP(c1.y, 10) CONVSTEP(c1.z, 12) CONVSTEP(c1.w, 14)
        CONVSTEP(c2.x, 16) CONVSTEP(c2.y, 18) CONVSTEP(c2.z, 20) CONVSTEP(c2.w, 22)
        { float lo_ = __uint_as_float((unsigned)c3.x << 16);
          za0 = fmaf(lo_, h0[24], za0); za1 = fmaf(lo_, h1[24], za1); }
        Hs[(tt0*32 + u) * HP + k] = f2bf((za0 + zb0) * gv);
        Hs[(tt1*32 + u) * HP + k] = f2bf((za1 + zb1) * gv);
        ap = np; c0 = n0; c1 = n1; c2 = n2; c3 = n3;
    }
#undef CONVSTEP
    __syncthreads();

    // ---- LN stats: thread r<128 reduces row (tt=r>>5, u=r&31), u<25 active ----
    if (tid < 128) {
        int u = tid & 31;
        if (u < VV) {
            const short4* zr = (const short4*)(Hs + tid * HP);
            float s = 0.f, s2 = 0.f;
            #pragma unroll 8
            for (int i = 0; i < KK/4; ++i) {
                short4 q = zr[i];
                float a = bf2f(q.x), bq = bf2f(q.y), c = bf2f(q.z), d = bf2f(q.w);
                s += a + bq + c + d;
                s2 = fmaf(a, a, fmaf(bq, bq, fmaf(c, c, fmaf(d, d, s2))));
            }
            float mu = s * (1.f / KK);
            float var = s2 * (1.f / KK) - mu * mu;
            ms[tid] = mu;
            rs[tid] = rsqrtf(var + 1e-5f);
        }
    }
    __syncthreads();

    // ---- epilogue: normalize + affine, coalesced nontemporal fp32 stores ----
    float w2 = lw[k], b2v = lb[k];
    #pragma unroll 1
    for (int tt = tt0; tt <= tt1; ++tt) {
        float* ob = out + (((size_t)(b * TT + t0 + tt)) * VV) * KK + k;
        #pragma unroll
        for (int u = 0; u < VV; ++u) {
            float val = (bf2f(Hs[(tt*32 + u) * HP + k]) - ms[tt*32 + u]) * rs[tt*32 + u] * w2 + b2v;
            __builtin_nontemporal_store(val, ob + (size_t)u * KK);
        }
    }
}

// ---------------------------------------------------------------------------
extern "C" void kernel_launch(void* const* d_in, const int* in_sizes, int n_in,
                              void* d_out, int out_size, void* d_ws, size_t ws_size,
                              hipStream_t stream) {
    const float* x      = (const float*)d_in[0];
    const float* A      = (const float*)d_in[1];
    const float* lam    = (const float*)d_in[2];
    const float* phi_w  = (const float*)d_in[3];
    const float* phi_b  = (const float*)d_in[4];
    const float* th_w   = (const float*)d_in[5];
    const float* th_b   = (const float*)d_in[6];
    const float* ka_w   = (const float*)d_in[7];
    const float* ka_b   = (const float*)d_in[8];
    const float* xi_w   = (const float*)d_in[9];
    const float* xi_b   = (const float*)d_in[10];
    const float* q_w    = (const float*)d_in[11];
    const float* q_b    = (const float*)d_in[12];
    const float* k_w    = (const float*)d_in[13];
    const float* k_b    = (const float*)d_in[14];
    const float* ca1_w  = (const float*)d_in[15];
    const float* ca1_b  = (const float*)d_in[16];
    const float* ln1_w  = (const float*)d_in[17];
    const float* ln1_b  = (const float*)d_in[18];
    const float* ca2_w  = (const float*)d_in[19];
    const float* ca2_b  = (const float*)d_in[20];
    const float* ln2_w  = (const float*)d_in[21];
    const float* ln2_b  = (const float*)d_in[22];
    float* out = (float*)d_out;
    float* ws  = (float*)d_ws;
    short* Atv = (short*)(ws + WS_AT);
    short* BT  = (short*)(ws + WS_BT);

    kBT <<<64, 256, 0, stream>>>(xi_w, BT);
    kA  <<<BB*VV, 256, 0, stream>>>(x, ws + WS_XBAR);
    kB1 <<<BB*VV, 128, 0, stream>>>(ws + WS_XBAR, phi_w, phi_b, th_w, th_b, xi_w, xi_b,
                                    ws + WS_PHIX, ws + WS_THX, ws + WS_HBAR);
    kB2 <<<BB*VV, 128, 0, stream>>>(ws + WS_PHIX, ws + WS_THX, ka_w, ka_b, A, lam, Atv);
    kB34<<<BB*VV, 128, 0, stream>>>(Atv, ws + WS_HBAR, q_w, q_b, k_w, k_b,
                                    ws + WS_XQ, ws + WS_XK);
    kB5 <<<BB*KK, 64, 0, stream>>>(ws + WS_XQ, ws + WS_XK, ws + WS_HBAR, ws + WS_CA);
    kB6 <<<BB, 128, 0, stream>>>(ws + WS_CA, ca1_w, ca1_b, ln1_w, ln1_b, ca2_w, ca2_b, ws + WS_GATE);
    kF  <<<BB*(TT/TG), 256, 0, stream>>>(x, BT, xi_b, Atv, ws + WS_GATE, ln2_w, ln2_b, out);
}

// Round 4
// 409.007 us; speedup vs baseline: 1.1538x; 1.0090x over previous
//
#include <hip/hip_runtime.h>
#include <hip/hip_bf16.h>
#include <math.h>

// Problem constants
#define BB 64
#define TT 128
#define VV 25
#define CC 128
#define KK 128
#define RR 32
#define TG 4    // timesteps per kF block (= waves per block)

typedef __attribute__((ext_vector_type(8))) short bf16x8;
typedef __attribute__((ext_vector_type(4))) float f32x4;
typedef __attribute__((ext_vector_type(2))) float f32x2;

// bf16 helpers (RNE)
static __device__ __forceinline__ short f2bf(float f) {
    union { float f; unsigned u; } a; a.f = f;
    unsigned r = a.u + 0x7fffu + ((a.u >> 16) & 1u);
    return (short)(r >> 16);
}
static __device__ __forceinline__ float bf2f(short s) {
    union { unsigned u; float f; } a; a.u = ((unsigned)(unsigned short)s) << 16;
    return a.f;
}

// Workspace layout (float offsets)
#define WS_XBAR 0              // [B,V,C]      204800
#define WS_PHIX 204800         // [B,V,K]      204800
#define WS_THX  409600         // [B,V,K]      204800
#define WS_HBAR 614400         // [B,V,K]      204800
#define WS_XQ   819200         // [B,V,K]      204800
#define WS_XK   1024000        // [B,V,K]      204800
#define WS_CA   1228800        // [B,K]        8192
#define WS_GATE 1236992        // [B,K]        8192
#define WS_AT   1245184        // Atv [B][V=u][K][32 v-padded] bf16: 6.55M shorts (3.28M floats)
#define WS_BT   6365184        // [K][C]       16384 bf16 (xi_w transposed)

// ---------------------------------------------------------------------------
// Kernel A: xbar[b,v,c] = mean_t x[b,t,v,c].  One 256-thr block per (b,v) row.
// Blocks 0..63 additionally emit BT[n][c] = bf16(xi_w[c][n]) (64*256 = 16384).
__global__ __launch_bounds__(256) void kA(const float* __restrict__ x, float* __restrict__ xbar,
                                          const float* __restrict__ xw, short* __restrict__ BT) {
    if (blockIdx.x < 64) {
        int i0 = threadIdx.x + blockIdx.x * 256;
        int n = i0 >> 7, c = i0 & 127;
        BT[i0] = f2bf(xw[c * KK + n]);
    }
    int row = blockIdx.x;                 // b*V + v
    int b = row / VV, v = row % VV;
    int tq = threadIdx.x >> 5, cq = threadIdx.x & 31;
    const float4* x4 = (const float4*)x;
    size_t base = ((size_t)b * TT * VV + v) * 32 + cq;
    float sx = 0.f, sy = 0.f, sz = 0.f, sw = 0.f;
    #pragma unroll 4
    for (int i = 0; i < 16; ++i) {
        float4 a = x4[base + (size_t)(tq * 16 + i) * VV * 32];
        sx += a.x; sy += a.y; sz += a.z; sw += a.w;
    }
    __shared__ float4 red[8][32];
    red[tq][cq] = (float4){sx, sy, sz, sw};
    __syncthreads();
    if (tq == 0) {
        float4 o = red[0][cq];
        #pragma unroll
        for (int j = 1; j < 8; ++j) {
            float4 a = red[j][cq];
            o.x += a.x; o.y += a.y; o.z += a.z; o.w += a.w;
        }
        o.x *= (1.f/TT); o.y *= (1.f/TT); o.z *= (1.f/TT); o.w *= (1.f/TT);
        ((float4*)xbar)[(size_t)row * 32 + cq] = o;
    }
}

// ---------------------------------------------------------------------------
// Kernel B1: per (b,v): phi_x / theta_x / Hbar rows from xbar.
__global__ __launch_bounds__(128) void kB1(const float* __restrict__ xbar,
        const float* __restrict__ pw, const float* __restrict__ pb,
        const float* __restrict__ tw, const float* __restrict__ tb,
        const float* __restrict__ xw, const float* __restrict__ xbias,
        float* __restrict__ phix, float* __restrict__ thx, float* __restrict__ hbar) {
    int bv = blockIdx.x;
    int k = threadIdx.x;
    __shared__ float xv[CC];
    xv[k] = xbar[(size_t)bv * CC + k];
    __syncthreads();
    float sp = pb[k], st = tb[k], sh = xbias[k];
    #pragma unroll 4
    for (int c = 0; c < CC; ++c) {
        float xc = xv[c];
        sp = fmaf(xc, pw[c*KK + k], sp);
        st = fmaf(xc, tw[c*KK + k], st);
        sh = fmaf(xc, xw[c*KK + k], sh);
    }
    phix[(size_t)bv*KK + k] = sp;
    thx [(size_t)bv*KK + k] = st;
    hbar[(size_t)bv*KK + k] = sh;
}

// ---------------------------------------------------------------------------
// Kernel B2: per (b,i) block: Atv[b,i,k,v32] (bf16, v-padded to 32) for all j=v.
__global__ __launch_bounds__(128) void kB2(const float* __restrict__ phix, const float* __restrict__ thx,
        const float* __restrict__ kw, const float* __restrict__ kb,
        const float* __restrict__ A, const float* __restrict__ lam,
        short* __restrict__ Atv) {
    int bi = blockIdx.x;                 // b*V + i
    int b = bi / VV, i = bi % VV;
    int k = threadIdx.x;
    __shared__ float f[VV][132];
    float ph = phix[((size_t)b*VV + i)*KK + k];
    #pragma unroll 5
    for (int j = 0; j < VV; ++j)
        f[j][k] = tanhf(ph - thx[((size_t)b*VV + j)*KK + k]);
    __syncthreads();
    float s[VV];
    float bias = kb[k];
    #pragma unroll
    for (int j = 0; j < VV; ++j) s[j] = bias;
    #pragma unroll 2
    for (int c = 0; c < CC; c += 4) {
        float w0 = kw[(c+0)*KK + k];
        float w1 = kw[(c+1)*KK + k];
        float w2 = kw[(c+2)*KK + k];
        float w3 = kw[(c+3)*KK + k];
        #pragma unroll
        for (int j = 0; j < VV; ++j) {
            float4 fv = *(const float4*)&f[j][c];
            float t = fmaf(fv.x, w0, fmaf(fv.y, w1, fmaf(fv.z, w2, fv.w * w3)));
            s[j] += t;
        }
    }
    float l = lam[0];
    float vals[32];
    #pragma unroll
    for (int j = 0; j < VV; ++j)
        vals[j] = A[((size_t)k*VV + i)*VV + j] + l * s[j];
    #pragma unroll
    for (int j = VV; j < 32; ++j) vals[j] = 0.f;
    unsigned dw[16];
    #pragma unroll
    for (int m = 0; m < 16; ++m)
        dw[m] = (unsigned)(unsigned short)f2bf(vals[2*m])
              | ((unsigned)(unsigned short)f2bf(vals[2*m+1]) << 16);
    uint4* dst = (uint4*)(Atv + ((size_t)bi * KK + k) * 32);
    dst[0] = make_uint4(dw[0],  dw[1],  dw[2],  dw[3]);
    dst[1] = make_uint4(dw[4],  dw[5],  dw[6],  dw[7]);
    dst[2] = make_uint4(dw[8],  dw[9],  dw[10], dw[11]);
    dst[3] = make_uint4(dw[12], dw[13], dw[14], dw[15]);
}

// ---------------------------------------------------------------------------
// Kernel B34: per (b,u): Zbar row (in LDS) then XQ/XK rows.
__global__ __launch_bounds__(128) void kB34(const short* __restrict__ Atv, const float* __restrict__ hbar,
        const float* __restrict__ qw, const float* __restrict__ qb,
        const float* __restrict__ kw, const float* __restrict__ kb,
        float* __restrict__ XQ, float* __restrict__ XK) {
    int bu = blockIdx.x;
    int b = bu / VV;
    int k = threadIdx.x;
    __shared__ float zb[132];
    const float* hb = hbar + (size_t)b * VV * KK + k;
    const uint4* av = (const uint4*)(Atv + ((size_t)bu * KK + k) * 32);
    uint4 a0 = av[0], a1 = av[1], a2 = av[2], a3 = av[3];
    float s = 0.f;
#define KB34S(dd, v0) { \
    float lo_ = __uint_as_float((unsigned)(dd) << 16); \
    float hi_ = __uint_as_float((unsigned)(dd) & 0xffff0000u); \
    s = fmaf(lo_, hb[(v0)*KK], s); s = fmaf(hi_, hb[((v0)+1)*KK], s); }
    KB34S(a0.x, 0)  KB34S(a0.y, 2)  KB34S(a0.z, 4)  KB34S(a0.w, 6)
    KB34S(a1.x, 8)  KB34S(a1.y, 10) KB34S(a1.z, 12) KB34S(a1.w, 14)
    KB34S(a2.x, 16) KB34S(a2.y, 18) KB34S(a2.z, 20) KB34S(a2.w, 22)
    { float lo_ = __uint_as_float((unsigned)a3.x << 16); s = fmaf(lo_, hb[24*KK], s); }
#undef KB34S
    zb[k] = s;
    __syncthreads();
    float q = qb[k], kk2 = kb[k];
    #pragma unroll 2
    for (int c = 0; c < CC; c += 4) {
        float4 zv = *(const float4*)&zb[c];
        float q0 = qw[(c+0)*KK + k], q1 = qw[(c+1)*KK + k];
        float q2 = qw[(c+2)*KK + k], q3 = qw[(c+3)*KK + k];
        float k0 = kw[(c+0)*KK + k], k1 = kw[(c+1)*KK + k];
        float k2 = kw[(c+2)*KK + k], k3 = kw[(c+3)*KK + k];
        q   = fmaf(zv.x, q0, fmaf(zv.y, q1, fmaf(zv.z, q2, fmaf(zv.w, q3, q))));
        kk2 = fmaf(zv.x, k0, fmaf(zv.y, k1, fmaf(zv.z, k2, fmaf(zv.w, k3, kk2))));
    }
    XQ[(size_t)bu*KK + k] = q;
    XK[(size_t)bu*KK + k] = kk2;
}

// ---------------------------------------------------------------------------
// Kernel B5: ca[b,k] = sum_v Hbar * mean_u softmax_v(q_u k_v / sqrt(T))
__global__ __launch_bounds__(64) void kB5(const float* __restrict__ XQ, const float* __restrict__ XK,
        const float* __restrict__ hbar, float* __restrict__ ca) {
    int b = blockIdx.x >> 7;
    int k = blockIdx.x & 127;
    int tid = threadIdx.x;
    __shared__ float qv[VV], kv[VV], hv[VV], m[VV], dinv[VV];
    if (tid < VV) {
        qv[tid] = XQ[((size_t)b*VV + tid)*KK + k];
        kv[tid] = XK[((size_t)b*VV + tid)*KK + k];
        hv[tid] = hbar[((size_t)b*VV + tid)*KK + k];
    }
    __syncthreads();
    const float invs = 0.08838834764831845f;   // 1/sqrt(128)
    if (tid < VV) {
        float q = qv[tid];
        float mx = -1e30f;
        #pragma unroll
        for (int v = 0; v < VV; ++v) mx = fmaxf(mx, q * kv[v] * invs);
        float d = 0.f;
        #pragma unroll
        for (int v = 0; v < VV; ++v) d += expf(q * kv[v] * invs - mx);
        m[tid] = mx; dinv[tid] = 1.f / d;
    }
    __syncthreads();
    float contrib = 0.f;
    if (tid < VV) {
        float kkv = kv[tid];
        float s = 0.f;
        #pragma unroll
        for (int u = 0; u < VV; ++u) s += expf(qv[u] * kkv * invs - m[u]) * dinv[u];
        contrib = s * (1.f / VV) * hv[tid];
    }
    #pragma unroll
    for (int off = 32; off > 0; off >>= 1) contrib += __shfl_down(contrib, off);
    if (tid == 0) ca[(size_t)b*KK + k] = contrib;
}

// ---------------------------------------------------------------------------
// Kernel B6: gate = sigmoid(gelu(LN(ca@ca1_w+ca1_b)) @ ca2_w + ca2_b)
__global__ __launch_bounds__(128) void kB6(const float* __restrict__ ca,
        const float* __restrict__ w1, const float* __restrict__ b1,
        const float* __restrict__ lw, const float* __restrict__ lb,
        const float* __restrict__ w2, const float* __restrict__ b2,
        float* __restrict__ gate) {
    int b = blockIdx.x;
    int tid = threadIdx.x;
    __shared__ float cas[KK], t1[RR], c1[RR];
    cas[tid] = ca[(size_t)b*KK + tid];
    __syncthreads();
    if (tid < RR) {
        float s = b1[tid];
        for (int c = 0; c < KK; ++c) s = fmaf(cas[c], w1[c*RR + tid], s);
        t1[tid] = s;
    }
    __syncthreads();
    if (tid < RR) {
        float mu = 0.f;
        #pragma unroll
        for (int j = 0; j < RR; ++j) mu += t1[j];
        mu *= (1.f / RR);
        float var = 0.f;
        #pragma unroll
        for (int j = 0; j < RR; ++j) { float d = t1[j] - mu; var = fmaf(d, d, var); }
        var *= (1.f / RR);
        float xn = (t1[tid] - mu) * rsqrtf(var + 1e-5f) * lw[tid] + lb[tid];
        c1[tid] = 0.5f * xn * (1.f + erff(xn * 0.70710678118654752f));
    }
    __syncthreads();
    float g = b2[tid];
    #pragma unroll
    for (int r = 0; r < RR; ++r) g = fmaf(c1[r], w2[r*KK + tid], g);
    gate[(size_t)b*KK + tid] = 1.f / (1.f + expf(-g));
}

// ---------------------------------------------------------------------------
// Kernel F (fused H+Z): block = (b, 4 timesteps), 256 threads / 4 waves.
// Phase 1: MFMA H (bit-hack f2bf conversions — no inline asm).
// Phase 2: conv with v_pk_fma_f32 (f32x2, pure C): per bf16-dword 2 unpack +
//          2 pk_fma = 4 instr / 8 FLOPs (was 6).  h pre-paired as f32x2;
//          pair 12 .y partner is At pad = 0.  z written directly to LDS,
//          LN + coalesced nontemporal stores as before.
#define HP 132  // LDS row pitch (shorts)
__global__ __launch_bounds__(256, 3) void kF(const float* __restrict__ x,
        const short* __restrict__ BT, const float* __restrict__ xbias,
        const short* __restrict__ Atv, const float* __restrict__ gate,
        const float* __restrict__ lw, const float* __restrict__ lb,
        float* __restrict__ out) {
    int b  = blockIdx.x >> 5;         // b-major: 32 consecutive blocks share b (L2 Atv reuse)
    int tg = blockIdx.x & 31;
    int t0 = tg * TG;
    int tid = threadIdx.x;
    int wave = tid >> 6, lane = tid & 63;
    int l15 = lane & 15, quad = lane >> 4;

    __shared__ short Hs[TG * 32 * HP];      // 33792 B
    __shared__ float ms[TG * 32], rs[TG * 32];

    // ---- Phase 1: MFMA H for timestep t0+wave ----
    {
        const float* xw_base = x + ((size_t)(b * TT + t0 + wave) * VV) * CC;
        f32x4 acc[2][8];
        #pragma unroll
        for (int rt = 0; rt < 2; ++rt)
            #pragma unroll
            for (int ct = 0; ct < 8; ++ct)
                acc[rt][ct] = (f32x4){0.f, 0.f, 0.f, 0.f};

        int va0 = l15;            // rt=0 A-row
        int va1 = 16 + l15;       // rt=1 A-row
        if (va1 > VV - 1) va1 = VV - 1;   // clamp pad rows (results unused)

        #pragma unroll
        for (int s = 0; s < 4; ++s) {
            bf16x8 afr[2];
            #pragma unroll
            for (int rt = 0; rt < 2; ++rt) {
                const float* ap = xw_base + (size_t)(rt ? va1 : va0) * CC + s*32 + quad*8;
                float4 a0 = *(const float4*)ap;
                float4 a1 = *(const float4*)(ap + 4);
                union { bf16x8 v; short h[8]; } u;
                u.h[0] = f2bf(a0.x); u.h[1] = f2bf(a0.y); u.h[2] = f2bf(a0.z); u.h[3] = f2bf(a0.w);
                u.h[4] = f2bf(a1.x); u.h[5] = f2bf(a1.y); u.h[6] = f2bf(a1.z); u.h[7] = f2bf(a1.w);
                afr[rt] = u.v;
            }
            #pragma unroll
            for (int ct = 0; ct < 8; ++ct) {
                bf16x8 bfr = *(const bf16x8*)(BT + (ct*16 + l15) * CC + s*32 + quad*8);
                acc[0][ct] = __builtin_amdgcn_mfma_f32_16x16x32_bf16(afr[0], bfr, acc[0][ct], 0, 0, 0);
                acc[1][ct] = __builtin_amdgcn_mfma_f32_16x16x32_bf16(afr[1], bfr, acc[1][ct], 0, 0, 0);
            }
        }
        // write H tile to LDS: row v = rt*16 + quad*4 + i, col k = ct*16 + l15
        #pragma unroll
        for (int ct = 0; ct < 8; ++ct) {
            float bias = xbias[ct*16 + l15];
            #pragma unroll
            for (int rt = 0; rt < 2; ++rt) {
                int vbase = rt*16 + quad*4;
                #pragma unroll
                for (int i = 0; i < 4; ++i)
                    Hs[(wave*32 + vbase + i) * HP + ct*16 + l15] = f2bf(acc[rt][ct][i] + bias);
            }
        }
    }

    // ---- Phase 2 setup: issue global loads early (independent of LDS) ----
    int k = tid & 127, g = tid >> 7;
    int tt0 = 2*g, tt1 = 2*g + 1;
    float gv = gate[(size_t)b * KK + k];
    const uint4* ap = (const uint4*)(Atv + ((size_t)(b * VV) * KK + k) * 32);
    uint4 c0 = ap[0], c1 = ap[1], c2 = ap[2], c3 = ap[3];   // u=0 tile in flight

    __syncthreads();   // H tile complete

    // h pairs: h0p[j] = (h[2j], h[2j+1]); pair 12 = (h[24], 0)
    f32x2 h0p[13], h1p[13];
    #pragma unroll
    for (int j = 0; j < 12; ++j) {
        h0p[j] = (f32x2){ bf2f(Hs[(tt0*32 + 2*j) * HP + k]), bf2f(Hs[(tt0*32 + 2*j+1) * HP + k]) };
        h1p[j] = (f32x2){ bf2f(Hs[(tt1*32 + 2*j) * HP + k]), bf2f(Hs[(tt1*32 + 2*j+1) * HP + k]) };
    }
    h0p[12] = (f32x2){ bf2f(Hs[(tt0*32 + 24) * HP + k]), 0.f };
    h1p[12] = (f32x2){ bf2f(Hs[(tt1*32 + 24) * HP + k]), 0.f };
    __syncthreads();   // all Hs reads done; rows free for z overwrite

#define CSTEP(dd, j) { \
    f32x2 at2; \
    at2.x = __uint_as_float((unsigned)(dd) << 16); \
    at2.y = __uint_as_float((unsigned)(dd) & 0xffff0000u); \
    acc0 += at2 * h0p[j]; \
    acc1 += at2 * h1p[j]; }

    #pragma unroll 1
    for (int u = 0; u < VV; ++u) {
        const uint4* np = ap + ((u < VV-1) ? (KK*4) : 0);   // prefetch u+1 (clamped)
        uint4 n0 = np[0], n1 = np[1], n2 = np[2], n3 = np[3];
        f32x2 acc0 = (f32x2){0.f, 0.f}, acc1 = (f32x2){0.f, 0.f};
        CSTEP(c0.x, 0)  CSTEP(c0.y, 1)  CSTEP(c0.z, 2)  CSTEP(c0.w, 3)
        CSTEP(c1.x, 4)  CSTEP(c1.y, 5)  CSTEP(c1.z, 6)  CSTEP(c1.w, 7)
        CSTEP(c2.x, 8)  CSTEP(c2.y, 9)  CSTEP(c2.z, 10) CSTEP(c2.w, 11)
        CSTEP(c3.x, 12)
        Hs[(tt0*32 + u) * HP + k] = f2bf((acc0.x + acc0.y) * gv);
        Hs[(tt1*32 + u) * HP + k] = f2bf((acc1.x + acc1.y) * gv);
        ap = np; c0 = n0; c1 = n1; c2 = n2; c3 = n3;
    }
#undef CSTEP
    __syncthreads();

    // ---- LN stats: thread r<128 reduces row (tt=r>>5, u=r&31), u<25 active ----
    if (tid < 128) {
        int u = tid & 31;
        if (u < VV) {
            const short4* zr = (const short4*)(Hs + tid * HP);
            float s = 0.f, s2 = 0.f;
            #pragma unroll 8
            for (int i = 0; i < KK/4; ++i) {
                short4 q = zr[i];
                float a = bf2f(q.x), bq = bf2f(q.y), c = bf2f(q.z), d = bf2f(q.w);
                s += a + bq + c + d;
                s2 = fmaf(a, a, fmaf(bq, bq, fmaf(c, c, fmaf(d, d, s2))));
            }
            float mu = s * (1.f / KK);
            float var = s2 * (1.f / KK) - mu * mu;
            ms[tid] = mu;
            rs[tid] = rsqrtf(var + 1e-5f);
        }
    }
    __syncthreads();

    // ---- epilogue: normalize + affine, coalesced nontemporal fp32 stores ----
    float w2 = lw[k], b2v = lb[k];
    #pragma unroll 1
    for (int tt = tt0; tt <= tt1; ++tt) {
        float* ob = out + (((size_t)(b * TT + t0 + tt)) * VV) * KK + k;
        #pragma unroll
        for (int u = 0; u < VV; ++u) {
            float val = (bf2f(Hs[(tt*32 + u) * HP + k]) - ms[tt*32 + u]) * rs[tt*32 + u] * w2 + b2v;
            __builtin_nontemporal_store(val, ob + (size_t)u * KK);
        }
    }
}

// ---------------------------------------------------------------------------
extern "C" void kernel_launch(void* const* d_in, const int* in_sizes, int n_in,
                              void* d_out, int out_size, void* d_ws, size_t ws_size,
                              hipStream_t stream) {
    const float* x      = (const float*)d_in[0];
    const float* A      = (const float*)d_in[1];
    const float* lam    = (const float*)d_in[2];
    const float* phi_w  = (const float*)d_in[3];
    const float* phi_b  = (const float*)d_in[4];
    const float* th_w   = (const float*)d_in[5];
    const float* th_b   = (const float*)d_in[6];
    const float* ka_w   = (const float*)d_in[7];
    const float* ka_b   = (const float*)d_in[8];
    const float* xi_w   = (const float*)d_in[9];
    const float* xi_b   = (const float*)d_in[10];
    const float* q_w    = (const float*)d_in[11];
    const float* q_b    = (const float*)d_in[12];
    const float* k_w    = (const float*)d_in[13];
    const float* k_b    = (const float*)d_in[14];
    const float* ca1_w  = (const float*)d_in[15];
    const float* ca1_b  = (const float*)d_in[16];
    const float* ln1_w  = (const float*)d_in[17];
    const float* ln1_b  = (const float*)d_in[18];
    const float* ca2_w  = (const float*)d_in[19];
    const float* ca2_b  = (const float*)d_in[20];
    const float* ln2_w  = (const float*)d_in[21];
    const float* ln2_b  = (const float*)d_in[22];
    float* out = (float*)d_out;
    float* ws  = (float*)d_ws;
    short* Atv = (short*)(ws + WS_AT);
    short* BT  = (short*)(ws + WS_BT);

    kA  <<<BB*VV, 256, 0, stream>>>(x, ws + WS_XBAR, xi_w, BT);
    kB1 <<<BB*VV, 128, 0, stream>>>(ws + WS_XBAR, phi_w, phi_b, th_w, th_b, xi_w, xi_b,
                                    ws + WS_PHIX, ws + WS_THX, ws + WS_HBAR);
    kB2 <<<BB*VV, 128, 0, stream>>>(ws + WS_PHIX, ws + WS_THX, ka_w, ka_b, A, lam, Atv);
    kB34<<<BB*VV, 128, 0, stream>>>(Atv, ws + WS_HBAR, q_w, q_b, k_w, k_b,
                                    ws + WS_XQ, ws + WS_XK);
    kB5 <<<BB*KK, 64, 0, stream>>>(ws + WS_XQ, ws + WS_XK, ws + WS_HBAR, ws + WS_CA);
    kB6 <<<BB, 128, 0, stream>>>(ws + WS_CA, ca1_w, ca1_b, ln1_w, ln1_b, ca2_w, ca2_b, ws + WS_GATE);
    kF  <<<BB*(TT/TG), 256, 0, stream>>>(x, BT, xi_b, Atv, ws + WS_GATE, ln2_w, ln2_b, out);
}